// Round 11
// baseline (103.607 us; speedup 1.0000x reference)
//
#include <hip/hip_runtime.h>

#define THRESH 0.95f
#define MAXL 64
#define RSTR 65     // record slots per batch: 64 labels + 1 spare
#define WVB  16     // waves (= batches) per scan block

__device__ __forceinline__ float rlane(float v, int lane) {
    return __uint_as_float(__builtin_amdgcn_readlane(__float_as_uint(v), lane));
}

// Kernel A v11 (= v10 with the writelane builtin replaced by lane-select):
// register-resident speculative-window scan, scalar-branch-only.
// One WAVE per batch, 16 waves/block (4 waves per SIMD -> dependent-add gaps
// of one wave are filled by the other three). All 64 lanes compute the serial
// chain redundantly (identical values), so every condition is wave-uniform:
// tests are written as __ballot(f) != 0, which compiles to s_cbranch with NO
// exec save/restore diamonds. Fire records are kept in TWO VGPRs via
// lane-select (record n -> lane n; v_cmp_eq + cndmask, predication not
// branching); the loop body touches no memory. One coalesced store_dwordx2
// per batch at the end.
// Window of 8: 8 chained adds are a bit-exact prefix of the reference chain
// while no fire occurs; alphas >= 0 (per-group sign check folded into the
// trigger) makes partials monotone -> single s8 > 0.95 test. Triggered
// windows replay the reference arithmetic exactly:
//   x = p + a; if (x > 0.95) { record pre; x = x - 1.0 }   (Sterbenz-exact)
__global__ __launch_bounds__(1024, 4) void cif_scan(
    const float* __restrict__ alphas, int T, int B,
    int* __restrict__ nf, uint2* __restrict__ recs) {
    int wv   = threadIdx.x >> 6;
    int lane = threadIdx.x & 63;
    int b = blockIdx.x * WVB + wv;
    if (b >= B) return;
    const float* arow = alphas + (size_t)b * T;
    uint2* rec = recs + (size_t)b * RSTR;

    float integ = 0.0f;
    int n = 0;                        // uniform fire count (scalar)
    unsigned vpre = 0u, vt = 0u;      // record regs: lane k holds record k

// exact reference step with register recording; all control flow scalar.
// record: lane n captures {pre, t} via compare-select (no branch, no memory)
#define FSTEP(CV, TT)                                                        \
    {                                                                        \
        float p = cur;                                                       \
        float x = p + (CV);                                                  \
        bool f = x > THRESH;                                                 \
        cur = f ? (x - 1.0f) : x;                                            \
        if (__ballot(f) != 0ull) {    /* uniform -> s_cbranch, no exec */    \
            bool sel = (lane == n) & (n < MAXL);                             \
            vpre = sel ? __float_as_uint(p) : vpre;                          \
            vt   = sel ? (unsigned)(TT)     : vt;                            \
            ++n;                                                             \
        }                                                                    \
    }

    int nwin = T >> 3;
    bool fast = ((((uintptr_t)arow) & 15) == 0) && (nwin >= 1);
    if (fast) {
        const float4* g4 = (const float4*)arow;
        int ngrp = (nwin + 63) >> 6;
        float4 z = make_float4(0.f, 0.f, 0.f, 0.f);
        float4 pa = z, pb = z, qa = z, qb = z;
        if (lane < nwin) { pa = g4[lane * 2]; pb = g4[lane * 2 + 1]; }
        for (int j = 0; j < ngrp; ++j) {
            int wbase = j << 6;
            int lim = nwin - wbase; if (lim > 64) lim = 64;
            if (j + 1 < ngrp) {                 // prefetch next 64-window group
                int nx = wbase + 64 + lane;
                qa = z; qb = z;
                if (nx < nwin) { qa = g4[nx * 2]; qb = g4[nx * 2 + 1]; }
            }
            // any negative alpha in this group -> force exact path (monotone
            // shortcut invalid); uniform across wave after ballot
            unsigned sg = __float_as_uint(pa.x) | __float_as_uint(pa.y) |
                          __float_as_uint(pa.z) | __float_as_uint(pa.w) |
                          __float_as_uint(pb.x) | __float_as_uint(pb.y) |
                          __float_as_uint(pb.z) | __float_as_uint(pb.w);
            bool gneg = __ballot(((sg >> 31) & 1u) != 0u) != 0ull;

            for (int w2 = 0; w2 < lim; ++w2) {
                float c0 = rlane(pa.x, w2), c1 = rlane(pa.y, w2);
                float c2 = rlane(pa.z, w2), c3 = rlane(pa.w, w2);
                float c4 = rlane(pb.x, w2), c5 = rlane(pb.y, w2);
                float c6 = rlane(pb.z, w2), c7 = rlane(pb.w, w2);
                float s1 = integ + c0, s2 = s1 + c1;
                float s3 = s2 + c2,    s4 = s3 + c3;
                float s5 = s4 + c4,    s6 = s5 + c5;
                float s7 = s6 + c6,    s8 = s7 + c7;
                bool trig = (s8 > THRESH) | gneg;
                if (__ballot(trig) != 0ull) {   // uniform -> scalar branch
                    int tb = (wbase + w2) << 3;
                    float cur = integ;
                    FSTEP(c0, tb)     FSTEP(c1, tb + 1)
                    FSTEP(c2, tb + 2) FSTEP(c3, tb + 3)
                    FSTEP(c4, tb + 4) FSTEP(c5, tb + 5)
                    FSTEP(c6, tb + 6) FSTEP(c7, tb + 7)
                    integ = cur;
                } else {
                    integ = s8;
                }
            }
            pa = qa; pb = qb;
        }
    }
    // tail (T % 8, none for T=2000) — or whole scan if fast path ineligible
    {
        float cur = integ;
        for (int t = fast ? (nwin << 3) : 0; t < T; ++t) {
            float a = arow[t];
            FSTEP(a, t)
        }
        integ = cur;
    }
#undef FSTEP

    int nfb = (n < MAXL) ? n : MAXL;
    if (lane < nfb) rec[lane] = make_uint2(vpre, vt);  // one coalesced store
    if (lane == 0) nf[b] = nfb;
}

// Kernel B (unchanged; absmax 0.0 in rounds 1-9; ~12 µs, L3-BW-bound):
// one block per (batch,label), float4 over H, ascending-t accumulation.
//   out[b,k,:] = rem[k-1]*h[tp] + sum_{t in (tp,tf)} a_t*h[t] + dc_k*h[tf]
// dc = 1 - pre (bit-exact reference dist_completion), rem = a[tp] - dc_prev.
// Labels k >= fire count write zeros (d_out is poisoned by the harness).
__global__ __launch_bounds__(128) void cif_gather(
    const float* __restrict__ hidden, const float* __restrict__ alphas,
    int T, int H,
    const int* __restrict__ nf, const uint2* __restrict__ recs,
    float* __restrict__ out) {
    int b = blockIdx.x >> 6;
    int k = blockIdx.x & (MAXL - 1);

    int valid = (k < nf[b]);
    int tf = 0, t0 = 0, tp = 0;
    float rw = 0.0f, cw = 0.0f;
    const float* arow = alphas + (size_t)b * T;
    if (valid) {
        uint2 r = recs[(size_t)b * RSTR + k];
        cw = 1.0f - __uint_as_float(r.x);            // dc = 1 - pre, bit-exact
        tf = (int)r.y;
        if (k > 0) {
            uint2 rp = recs[(size_t)b * RSTR + k - 1];
            tp = (int)rp.y;
            float dcp = 1.0f - __uint_as_float(rp.x);
            rw = arow[tp] - dcp;                     // rem = a - dc, bit-exact
            t0 = tp + 1;
        }
    }

    if ((H & 3) == 0) {
        int W = H >> 2;
        const float4* hb4 = (const float4*)(hidden + (size_t)b * T * H);
        float4* out4 = (float4*)(out + (size_t)blockIdx.x * H);
        for (int h4 = threadIdx.x; h4 < W; h4 += blockDim.x) {
            float4 acc = make_float4(0.f, 0.f, 0.f, 0.f);
            if (valid) {
                if (k > 0) {
                    float4 m = hb4[(size_t)tp * W + h4];
                    acc.x = rw * m.x; acc.y = rw * m.y;
                    acc.z = rw * m.z; acc.w = rw * m.w;
                }
                for (int t = t0; t < tf; ++t) {
                    float4 m = hb4[(size_t)t * W + h4];
                    float a = arow[t];
                    acc.x += a * m.x; acc.y += a * m.y;
                    acc.z += a * m.z; acc.w += a * m.w;
                }
                float4 m = hb4[(size_t)tf * W + h4];
                acc.x += cw * m.x; acc.y += cw * m.y;
                acc.z += cw * m.z; acc.w += cw * m.w;
            }
            out4[h4] = acc;
        }
    } else {
        const float* hb = hidden + (size_t)b * T * H;
        size_t obase = (size_t)blockIdx.x * H;
        for (int h = threadIdx.x; h < H; h += blockDim.x) {
            float acc = 0.0f;
            if (valid) {
                if (k > 0) acc = rw * hb[(size_t)tp * H + h];
                for (int t = t0; t < tf; ++t)
                    acc += arow[t] * hb[(size_t)t * H + h];
                acc += cw * hb[(size_t)tf * H + h];
            }
            out[obase + h] = acc;
        }
    }
}

extern "C" void kernel_launch(void* const* d_in, const int* in_sizes, int n_in,
                              void* d_out, int out_size, void* d_ws, size_t ws_size,
                              hipStream_t stream) {
    const float* hidden = (const float*)d_in[0];
    const float* alphas = (const float*)d_in[1];
    float* out = (float*)d_out;

    long BT  = in_sizes[1];          // B*T
    long BTH = in_sizes[0];          // B*T*H
    int H = (int)(BTH / BT);         // 512
    int B = (int)((long)out_size / ((long)MAXL * H)); // 32
    int T = (int)(BT / B);           // 2000

    char* ws = (char*)d_ws;
    int*   nf   = (int*)ws;                          // B ints
    uint2* recs = (uint2*)(ws + 256);                // B*RSTR uint2

    int nblk = (B + WVB - 1) / WVB;
    cif_scan<<<nblk, WVB * 64, 0, stream>>>(alphas, T, B, nf, recs);
    cif_gather<<<B * MAXL, 128, 0, stream>>>(hidden, alphas, T, H, nf, recs, out);
}

// Round 12
// 80.011 us; speedup vs baseline: 1.2949x; 1.2949x over previous
//
#include <hip/hip_runtime.h>

#define THRESH 0.95f
#define MAXL 64
#define RSTR 65      // global record slots per batch (64 + spare)
#define RECN 96      // LDS record slots (clamped; fires ~64 by construction)
#define SAPAD 2064   // staged floats: supports T <= 2048, +16 prefetch pad

// Kernel A v12: single-lane VGPR chain + wave-parallel drain.
// One block (= one wave) per batch. Alphas staged once into LDS.
// Lane 0 runs the bit-exact chain in a fully-unrolled 64-step block:
//   rot[j] = integ          (pre value -> LDS ring, compile-time offset)
//   x = integ + a           (reference op order)
//   y = x - 1.0f            (Sterbenz-exact, off-chain)
//   f = x > 0.95
//   wmask |= ballot(f)<<j   (2 SALU, compile-time shift)
//   integ = f ? y : x       (cndmask)
// -> no record-index arithmetic on the chain (v7's vcc->n->addr serializer),
// no memory scatter (v6), no scalarization (v11: all chain values divergent
// by construction -> VGPRs). After each 64-block, ALL 64 lanes drain: lane j
// tests bit j of wmask, mbcnt compacts, reads rot[j], writes {pre,t} to the
// LDS record list. dc=1-pre and rem=a-dc are recomputed in the gather
// (bit-exact, proven rounds 6-11).
__global__ __launch_bounds__(64) void cif_scan(
    const float* __restrict__ alphas, int T, int B,
    int* __restrict__ nf, uint2* __restrict__ recs) {
    __shared__ __align__(16) float sa[SAPAD];
    __shared__ float rot[64];
    __shared__ uint2 rl[RECN];
    int b = blockIdx.x;
    int lane = threadIdx.x;
    const float* arow = alphas + (size_t)b * T;

    // ---- stage row into LDS (coalesced); zero the pad
    if ((((uintptr_t)arow) & 15) == 0 && (T & 3) == 0) {
        const float4* g4 = (const float4*)arow;
        int n4 = T >> 2;
        for (int i = lane; i < n4; i += 64) ((float4*)sa)[i] = g4[i];
    } else {
        for (int i = lane; i < T; i += 64) sa[i] = arow[i];
    }
    for (int i = T + lane; i < SAPAD; i += 64) sa[i] = 0.0f;
    __syncthreads();

    float integ = 0.0f;
    unsigned n = 0;        // uniform fire count (updated in drain, all lanes)

#define ONES(JJ, AV)                                                         \
    {                                                                        \
        rot[JJ] = integ;                                                     \
        float x = integ + (AV);                                              \
        float y = x - 1.0f;                                                  \
        bool f = x > THRESH;                                                 \
        wmask |= __ballot(f) << (JJ);                                        \
        integ = f ? y : x;                                                   \
    }

#define DRAIN(T0)                                                            \
    {                                                                        \
        unsigned mlo = __builtin_amdgcn_readfirstlane((unsigned)wmask);      \
        unsigned mhi = __builtin_amdgcn_readfirstlane(                       \
            (unsigned)(wmask >> 32));                                        \
        unsigned long long m = ((unsigned long long)mhi << 32) | mlo;        \
        if (m) {                                                             \
            unsigned pref = __builtin_amdgcn_mbcnt_hi(                       \
                mhi, __builtin_amdgcn_mbcnt_lo(mlo, 0));                     \
            if ((m >> lane) & 1ull) {                                        \
                unsigned idx = n + pref;                                     \
                if (idx >= RECN) idx = RECN - 1;                             \
                rl[idx] = make_uint2(__float_as_uint(rot[lane]),             \
                                     (unsigned)((T0) + lane));               \
            }                                                                \
            n += (unsigned)__popcll(m);                                      \
        }                                                                    \
    }

    int nblk = T >> 6;
    for (int blk = 0; blk < nblk; ++blk) {
        int t0 = blk << 6;
        unsigned long long wmask = 0ull;
        if (lane == 0) {
            const float4* s4 = (const float4*)sa;
            int base = t0 >> 2;
            float4 v[16];
            #pragma unroll
            for (int i = 0; i < 16; ++i) v[i] = s4[base + i];
            #pragma unroll
            for (int g = 0; g < 16; ++g) {
                ONES(g * 4 + 0, v[g].x)
                ONES(g * 4 + 1, v[g].y)
                ONES(g * 4 + 2, v[g].z)
                ONES(g * 4 + 3, v[g].w)
            }
        }
        DRAIN(t0)
    }
    // tail (T % 64 steps; 16 for T=2000)
    int ttail = nblk << 6;
    if (ttail < T) {
        unsigned long long wmask = 0ull;
        if (lane == 0) {
            int cnt = T - ttail;
            for (int j = 0; j < cnt; ++j) {
                float a = sa[ttail + j];
                rot[j] = integ;
                float x = integ + a;
                float y = x - 1.0f;
                bool f = x > THRESH;
                wmask |= __ballot(f) << j;
                integ = f ? y : x;
            }
        }
        DRAIN(ttail)
    }
#undef ONES
#undef DRAIN

    unsigned nn = (n < 64u) ? n : 64u;
    if (lane < (int)nn) recs[(size_t)b * RSTR + lane] = rl[lane];
    if (lane == 0) nf[b] = (int)nn;
}

// Kernel B (unchanged; absmax 0.0 in rounds 1-11; ~12 µs, L3-BW-bound):
// one block per (batch,label), float4 over H, ascending-t accumulation.
//   out[b,k,:] = rem[k-1]*h[tp] + sum_{t in (tp,tf)} a_t*h[t] + dc_k*h[tf]
// dc = 1 - pre (bit-exact reference dist_completion), rem = a[tp] - dc_prev.
// Labels k >= fire count write zeros (d_out is poisoned by the harness).
__global__ __launch_bounds__(128) void cif_gather(
    const float* __restrict__ hidden, const float* __restrict__ alphas,
    int T, int H,
    const int* __restrict__ nf, const uint2* __restrict__ recs,
    float* __restrict__ out) {
    int b = blockIdx.x >> 6;
    int k = blockIdx.x & (MAXL - 1);

    int valid = (k < nf[b]);
    int tf = 0, t0 = 0, tp = 0;
    float rw = 0.0f, cw = 0.0f;
    const float* arow = alphas + (size_t)b * T;
    if (valid) {
        uint2 r = recs[(size_t)b * RSTR + k];
        cw = 1.0f - __uint_as_float(r.x);            // dc = 1 - pre, bit-exact
        tf = (int)r.y;
        if (k > 0) {
            uint2 rp = recs[(size_t)b * RSTR + k - 1];
            tp = (int)rp.y;
            float dcp = 1.0f - __uint_as_float(rp.x);
            rw = arow[tp] - dcp;                     // rem = a - dc, bit-exact
            t0 = tp + 1;
        }
    }

    if ((H & 3) == 0) {
        int W = H >> 2;
        const float4* hb4 = (const float4*)(hidden + (size_t)b * T * H);
        float4* out4 = (float4*)(out + (size_t)blockIdx.x * H);
        for (int h4 = threadIdx.x; h4 < W; h4 += blockDim.x) {
            float4 acc = make_float4(0.f, 0.f, 0.f, 0.f);
            if (valid) {
                if (k > 0) {
                    float4 m = hb4[(size_t)tp * W + h4];
                    acc.x = rw * m.x; acc.y = rw * m.y;
                    acc.z = rw * m.z; acc.w = rw * m.w;
                }
                for (int t = t0; t < tf; ++t) {
                    float4 m = hb4[(size_t)t * W + h4];
                    float a = arow[t];
                    acc.x += a * m.x; acc.y += a * m.y;
                    acc.z += a * m.z; acc.w += a * m.w;
                }
                float4 m = hb4[(size_t)tf * W + h4];
                acc.x += cw * m.x; acc.y += cw * m.y;
                acc.z += cw * m.z; acc.w += cw * m.w;
            }
            out4[h4] = acc;
        }
    } else {
        const float* hb = hidden + (size_t)b * T * H;
        size_t obase = (size_t)blockIdx.x * H;
        for (int h = threadIdx.x; h < H; h += blockDim.x) {
            float acc = 0.0f;
            if (valid) {
                if (k > 0) acc = rw * hb[(size_t)tp * H + h];
                for (int t = t0; t < tf; ++t)
                    acc += arow[t] * hb[(size_t)t * H + h];
                acc += cw * hb[(size_t)tf * H + h];
            }
            out[obase + h] = acc;
        }
    }
}

extern "C" void kernel_launch(void* const* d_in, const int* in_sizes, int n_in,
                              void* d_out, int out_size, void* d_ws, size_t ws_size,
                              hipStream_t stream) {
    const float* hidden = (const float*)d_in[0];
    const float* alphas = (const float*)d_in[1];
    float* out = (float*)d_out;

    long BT  = in_sizes[1];          // B*T
    long BTH = in_sizes[0];          // B*T*H
    int H = (int)(BTH / BT);         // 512
    int B = (int)((long)out_size / ((long)MAXL * H)); // 32
    int T = (int)(BT / B);           // 2000 (<= 2048 for the staged path)

    char* ws = (char*)d_ws;
    int*   nf   = (int*)ws;                          // B ints
    uint2* recs = (uint2*)(ws + 256);                // B*RSTR uint2

    cif_scan<<<B, 64, 0, stream>>>(alphas, T, B, nf, recs);
    cif_gather<<<B * MAXL, 128, 0, stream>>>(hidden, alphas, T, H, nf, recs, out);
}